// Round 8
// baseline (186.809 us; speedup 1.0000x reference)
//
#include <hip/hip_runtime.h>

typedef float f32x4 __attribute__((ext_vector_type(4)));
typedef short bf16x8 __attribute__((ext_vector_type(8)));

#define MFMA_BF16(a, b, c) __builtin_amdgcn_mfma_f32_16x16x32_bf16((a), (b), (c), 0, 0, 0)

#define GLDS16(gp, lp) __builtin_amdgcn_global_load_lds( \
    (const __attribute__((address_space(1))) unsigned int*)(gp), \
    (__attribute__((address_space(3))) unsigned int*)(lp), 16, 0, 0)

__device__ __forceinline__ ushort f2bf(float f) {
    unsigned int u = __float_as_uint(f);
    return (ushort)((u + 0x7FFFu + ((u >> 16) & 1u)) >> 16);
}

__device__ __forceinline__ float fexp2(float x) {
#if __has_builtin(__builtin_amdgcn_exp2f)
    return __builtin_amdgcn_exp2f(x);
#else
    return exp2f(x);
#endif
}

// ---------------- prep: cvt x + transpose/cvt both weight matrices ----------------
__global__ __launch_bounds__(256) void prep_kernel(
    const float* __restrict__ x, const float* __restrict__ wq, const float* __restrict__ wo,
    ushort* __restrict__ xb, ushort* __restrict__ wqbt, ushort* __restrict__ wobt)
{
    __shared__ float tile[32][33];
    const int bid = blockIdx.x;
    if (bid < 2048) {
        const float4* src = (const float4*)x;
        ushort4* dst = (ushort4*)xb;
        for (int i = bid * 256 + threadIdx.x; i < 1572864; i += 2048 * 256) {
            float4 v = src[i];
            ushort4 o;
            o.x = f2bf(v.x); o.y = f2bf(v.y); o.z = f2bf(v.z); o.w = f2bf(v.w);
            dst[i] = o;
        }
        return;
    }
    const float* src; ushort* dst; int K, N, bx, by;
    if (bid < 3776) {
        const int L = bid - 2048;
        src = wq; dst = wqbt; K = 768; N = 2304; bx = L % 72; by = L / 72;
    } else {
        const int L = bid - 3776;
        src = wo; dst = wobt; K = 768; N = 768; bx = L % 24; by = L / 24;
    }
    const int n0 = bx * 32, k0 = by * 32;
    const int c = threadIdx.x & 31, rb = threadIdx.x >> 5;
    #pragma unroll
    for (int i = 0; i < 4; ++i)
        tile[i * 8 + rb][c] = src[(size_t)(k0 + i * 8 + rb) * N + n0 + c];
    __syncthreads();
    #pragma unroll
    for (int i = 0; i < 4; ++i) {
        int nr = i * 8 + rb;
        dst[(size_t)(n0 + nr) * K + k0 + c] = f2bf(tile[c][nr]);
    }
}

// ---------------- GEMM1: 256x256xBK64, 8 waves, 8-phase counted-vmcnt (m201 port) ----------------
// grid 288 (xcd-swizzled), block 512, 128KB LDS (1 block/CU).
__global__ __launch_bounds__(512, 2) void gemm_qkv_mfma(
    const ushort* __restrict__ A, const ushort* __restrict__ Bt,
    ushort* __restrict__ Qo, ushort* __restrict__ Ko, ushort* __restrict__ Vo)
{
    __shared__ ushort Abuf[2][16384];   // [256][64] bf16, slot-swizzled, 32KB each
    __shared__ ushort Bbuf[2][16384];
    const int tid = threadIdx.x, lane = tid & 63;
    const int wv = tid >> 6, lo = lane & 15, hi = lane >> 4;
    const int wr = wv >> 2, wc = wv & 3;        // 2M x 4N waves; 128x64 per wave
    const int L = blockIdx.x;
    const int nid = (L & 7) * 36 + (L >> 3);    // bijective: 288 % 8 == 0
    const int m0 = (nid / 9) * 256, n0 = (nid % 9) * 256;

    const int region = n0 / 768;                // 0:Q 1:K 2:V (256-tiles never span regions)

    // stage one half-tile (128 rows x 64 cols) = 2 glds/wave
    auto stageA = [&](int bi, int half, int kt) {
        #pragma unroll
        for (int c = 0; c < 2; ++c) {
            const int cl = c * 512 + tid;            // chunk-local 0..1023
            const int row = half * 128 + (cl >> 3), sl = cl & 7;
            GLDS16(A + (size_t)(m0 + row) * 768 + kt * 64 + ((sl ^ (row & 7)) * 8),
                   &Abuf[bi][(half * 1024 + c * 512 + (tid & 448)) * 8]);
        }
    };
    auto stageB = [&](int bi, int half, int kt) {
        #pragma unroll
        for (int c = 0; c < 2; ++c) {
            const int cl = c * 512 + tid;
            const int row = half * 128 + (cl >> 3), sl = cl & 7;
            GLDS16(Bt + (size_t)(n0 + row) * 768 + kt * 64 + ((sl ^ (row & 7)) * 8),
                   &Bbuf[bi][(half * 1024 + c * 512 + (tid & 448)) * 8]);
        }
    };

    f32x4 acc[8][4];
    #pragma unroll
    for (int i = 0; i < 8; ++i)
        #pragma unroll
        for (int j = 0; j < 4; ++j)
            acc[i][j] = (f32x4){0.f, 0.f, 0.f, 0.f};

    // prologue: B[0], A[0], B[1]  (12 glds in flight)
    stageB(0, 0, 0); stageB(0, 1, 0);
    stageA(0, 0, 0); stageA(0, 1, 0);
    stageB(1, 0, 1); stageB(1, 1, 1);
    asm volatile("s_waitcnt vmcnt(4)" ::: "memory");   // B[0],A[0] landed
    __builtin_amdgcn_s_barrier();
    asm volatile("" ::: "memory");

    bf16x8 bfr[8];   // register-cached B frags of current K-tile [nj*2+ks]

    for (int it = 0; it < 6; ++it) {
        const int t1 = 2 * it + 1;
        const int kB2 = (2 * it + 2) % 12;   // wrap on last iter: harmless garbage stage
        const int kB3 = (2 * it + 3) % 12;

        // ---- phases 0..3: consume tile 2it from buf[0] ----
        #pragma unroll
        for (int q = 0; q < 4; ++q) {
            if (q == 0) {   // B-frags (8 reads)
                #pragma unroll
                for (int nj = 0; nj < 4; ++nj)
                    #pragma unroll
                    for (int ks = 0; ks < 2; ++ks) {
                        const int row = wc * 64 + nj * 16 + lo;
                        bfr[nj * 2 + ks] = *(const bf16x8*)&Bbuf[0][row * 64 + (((ks * 4 + hi) ^ (row & 7)) * 8)];
                    }
            }
            bf16x8 af[4];
            #pragma unroll
            for (int mm = 0; mm < 2; ++mm)
                #pragma unroll
                for (int ks = 0; ks < 2; ++ks) {
                    const int row = wr * 128 + (2 * q + mm) * 16 + lo;
                    af[mm * 2 + ks] = *(const bf16x8*)&Abuf[0][row * 64 + (((ks * 4 + hi) ^ (row & 7)) * 8)];
                }
            if (q == 0)      stageA(1, 0, t1);
            else if (q == 1) stageA(1, 1, t1);
            else if (q == 2) stageB(0, 0, kB2);
            else             stageB(0, 1, kB2);
            if (q == 0) asm volatile("s_waitcnt lgkmcnt(8)" ::: "memory");
            __builtin_amdgcn_s_barrier();
            asm volatile("s_waitcnt lgkmcnt(0)" ::: "memory");
            __builtin_amdgcn_s_setprio(1);
            if (region == 2) {
                #pragma unroll
                for (int mm = 0; mm < 2; ++mm)
                    #pragma unroll
                    for (int nj = 0; nj < 4; ++nj)
                        #pragma unroll
                        for (int ks = 0; ks < 2; ++ks)
                            acc[2 * q + mm][nj] = MFMA_BF16(af[mm * 2 + ks], bfr[nj * 2 + ks], acc[2 * q + mm][nj]);
            } else {
                #pragma unroll
                for (int mm = 0; mm < 2; ++mm)
                    #pragma unroll
                    for (int nj = 0; nj < 4; ++nj)
                        #pragma unroll
                        for (int ks = 0; ks < 2; ++ks)
                            acc[2 * q + mm][nj] = MFMA_BF16(bfr[nj * 2 + ks], af[mm * 2 + ks], acc[2 * q + mm][nj]);
            }
            __builtin_amdgcn_s_setprio(0);
            if (q == 3) asm volatile("s_waitcnt vmcnt(4)" ::: "memory");  // A[t1],B[t1] landed
            __builtin_amdgcn_s_barrier();
            asm volatile("" ::: "memory");
        }

        // ---- phases 4..7: consume tile 2it+1 from buf[1] ----
        #pragma unroll
        for (int q = 0; q < 4; ++q) {
            if (q == 0) {
                #pragma unroll
                for (int nj = 0; nj < 4; ++nj)
                    #pragma unroll
                    for (int ks = 0; ks < 2; ++ks) {
                        const int row = wc * 64 + nj * 16 + lo;
                        bfr[nj * 2 + ks] = *(const bf16x8*)&Bbuf[1][row * 64 + (((ks * 4 + hi) ^ (row & 7)) * 8)];
                    }
            }
            bf16x8 af[4];
            #pragma unroll
            for (int mm = 0; mm < 2; ++mm)
                #pragma unroll
                for (int ks = 0; ks < 2; ++ks) {
                    const int row = wr * 128 + (2 * q + mm) * 16 + lo;
                    af[mm * 2 + ks] = *(const bf16x8*)&Abuf[1][row * 64 + (((ks * 4 + hi) ^ (row & 7)) * 8)];
                }
            if (q == 0)      stageA(0, 0, kB2);
            else if (q == 1) stageA(0, 1, kB2);
            else if (q == 2) stageB(1, 0, kB3);
            else             stageB(1, 1, kB3);
            if (q == 0) asm volatile("s_waitcnt lgkmcnt(8)" ::: "memory");
            __builtin_amdgcn_s_barrier();
            asm volatile("s_waitcnt lgkmcnt(0)" ::: "memory");
            __builtin_amdgcn_s_setprio(1);
            if (region == 2) {
                #pragma unroll
                for (int mm = 0; mm < 2; ++mm)
                    #pragma unroll
                    for (int nj = 0; nj < 4; ++nj)
                        #pragma unroll
                        for (int ks = 0; ks < 2; ++ks)
                            acc[2 * q + mm][nj] = MFMA_BF16(af[mm * 2 + ks], bfr[nj * 2 + ks], acc[2 * q + mm][nj]);
            } else {
                #pragma unroll
                for (int mm = 0; mm < 2; ++mm)
                    #pragma unroll
                    for (int nj = 0; nj < 4; ++nj)
                        #pragma unroll
                        for (int ks = 0; ks < 2; ++ks)
                            acc[2 * q + mm][nj] = MFMA_BF16(bfr[nj * 2 + ks], af[mm * 2 + ks], acc[2 * q + mm][nj]);
            }
            __builtin_amdgcn_s_setprio(0);
            if (q == 3) asm volatile("s_waitcnt vmcnt(4)" ::: "memory");  // A[2it+2],B[2it+2] landed
            __builtin_amdgcn_s_barrier();
            asm volatile("" ::: "memory");
        }
    }
    asm volatile("s_waitcnt vmcnt(0)" ::: "memory");   // drain tail garbage stages

    const int h = ((n0 + wc * 64) % 768) >> 6;
    if (region == 2) {
        // natural: reg r -> s-row; ushort4 along s into V^T [d][s]
        #pragma unroll
        for (int mi = 0; mi < 8; ++mi) {
            const int m4 = m0 + wr * 128 + mi * 16 + hi * 4;
            const int b = m4 >> 10, s = m4 & 1023;
            #pragma unroll
            for (int nj = 0; nj < 4; ++nj) {
                const int d = nj * 16 + lo;
                ushort4 pk;
                pk.x = f2bf(acc[mi][nj][0]); pk.y = f2bf(acc[mi][nj][1]);
                pk.z = f2bf(acc[mi][nj][2]); pk.w = f2bf(acc[mi][nj][3]);
                *(ushort4*)&Vo[((size_t)(b * 12 + h) * 64 + d) * 1024 + s] = pk;
            }
        }
    } else {
        // swapped: reg r -> d; ushort4 along d into [s][d]
        ushort* dst = region ? Ko : Qo;
        const float sc = region ? 1.0f : 0.18033688011112042f;  // (1/8)*log2(e) for Q
        #pragma unroll
        for (int mi = 0; mi < 8; ++mi) {
            const int s_idx = m0 + wr * 128 + mi * 16 + lo;
            const int b = s_idx >> 10, s = s_idx & 1023;
            const size_t base = ((size_t)(b * 12 + h) * 1024 + s) * 64;
            #pragma unroll
            for (int nj = 0; nj < 4; ++nj) {
                ushort4 pk;
                pk.x = f2bf(acc[mi][nj][0] * sc); pk.y = f2bf(acc[mi][nj][1] * sc);
                pk.z = f2bf(acc[mi][nj][2] * sc); pk.w = f2bf(acc[mi][nj][3] * sc);
                *(ushort4*)&dst[base + nj * 16 + hi * 4] = pk;
            }
        }
    }
}

// ---------------- Flash attention, bf16 MFMA, no-max softmax, S^T trick, setprio ----------------
__global__ __launch_bounds__(256) void attn_mfma_kernel(
    const ushort* __restrict__ Qg, const ushort* __restrict__ Kg,
    const ushort* __restrict__ Vg, ushort* __restrict__ AO)
{
    __shared__ ushort Kl[2][4096];
    __shared__ ushort Vl[2][4096];
    __shared__ ushort Pl[4][32 * 72];

    const int tid = threadIdx.x, lane = tid & 63;
    const int wv = tid >> 6, lo = lane & 15, hi = lane >> 4;
    const int L = blockIdx.x;
    const int xcd = L & 7, g = L >> 3;
    const int qb = g / 12;
    const int bh = xcd * 12 + (g % 12);
    const int b = bh / 12, h = bh % 12;
    const size_t kvbase = (size_t)bh * (1024 * 64);

    bf16x8 qa[2][2];
    const int qrow0 = qb * 128 + wv * 32;
    #pragma unroll
    for (int mi = 0; mi < 2; ++mi)
        #pragma unroll
        for (int ks = 0; ks < 2; ++ks)
            qa[mi][ks] = *(const bf16x8*)&Qg[kvbase + (size_t)(qrow0 + mi * 16 + lo) * 64 + ks * 32 + hi * 8];

    f32x4 o[2][4];
    float lp[2] = {0.f, 0.f};
    #pragma unroll
    for (int mi = 0; mi < 2; ++mi)
        #pragma unroll
        for (int dj = 0; dj < 4; ++dj) o[mi][dj] = (f32x4){0.f, 0.f, 0.f, 0.f};

    auto stage = [&](int bi, int kt) {
        #pragma unroll
        for (int it = 0; it < 2; ++it) {
            const int p = it * 256 + tid;
            const int row = p >> 3, ch = (p & 7) ^ (row & 7);
            GLDS16(Kg + kvbase + (size_t)(kt + row) * 64 + ch * 8, &Kl[bi][(it * 256 + (tid & 192)) * 8]);
        }
        #pragma unroll
        for (int it = 0; it < 2; ++it) {
            const int p = it * 256 + tid;
            const int row = p >> 3, ch = (p & 7) ^ (row & 7);
            GLDS16(Vg + kvbase + (size_t)row * 1024 + kt + ch * 8, &Vl[bi][(it * 256 + (tid & 192)) * 8]);
        }
    };

    stage(0, 0);
    __syncthreads();

    for (int t = 0; t < 16; ++t) {
        const int cur = t & 1;
        if (t < 15) stage(cur ^ 1, (t + 1) * 64);

        f32x4 s[2][4];
        #pragma unroll
        for (int mi = 0; mi < 2; ++mi)
            #pragma unroll
            for (int nj = 0; nj < 4; ++nj) s[mi][nj] = (f32x4){0.f, 0.f, 0.f, 0.f};
        #pragma unroll
        for (int ks = 0; ks < 2; ++ks) {
            bf16x8 kb[4];
            #pragma unroll
            for (int nj = 0; nj < 4; ++nj) {
                const int key = nj * 16 + lo, c = ks * 4 + hi;
                kb[nj] = *(const bf16x8*)&Kl[cur][key * 64 + ((c ^ (key & 7)) * 8)];
            }
            __builtin_amdgcn_s_setprio(1);
            #pragma unroll
            for (int mi = 0; mi < 2; ++mi)
                #pragma unroll
                for (int nj = 0; nj < 4; ++nj)
                    s[mi][nj] = MFMA_BF16(kb[nj], qa[mi][ks], s[mi][nj]);
            __builtin_amdgcn_s_setprio(0);
        }

        #pragma unroll
        for (int mi = 0; mi < 2; ++mi) {
            #pragma unroll
            for (int nj = 0; nj < 4; ++nj) {
                const unsigned int u0 = __float_as_uint(fexp2(s[mi][nj][0]));
                const unsigned int u1 = __float_as_uint(fexp2(s[mi][nj][1]));
                const unsigned int u2 = __float_as_uint(fexp2(s[mi][nj][2]));
                const unsigned int u3 = __float_as_uint(fexp2(s[mi][nj][3]));
                const float t0 = __uint_as_float(u0 & 0xFFFF0000u);
                const float t1 = __uint_as_float(u1 & 0xFFFF0000u);
                const float t2 = __uint_as_float(u2 & 0xFFFF0000u);
                const float t3 = __uint_as_float(u3 & 0xFFFF0000u);
                lp[mi] += (t0 + t1) + (t2 + t3);
                ushort4 pk;
                pk.x = (ushort)(u0 >> 16); pk.y = (ushort)(u1 >> 16);
                pk.z = (ushort)(u2 >> 16); pk.w = (ushort)(u3 >> 16);
                *(ushort4*)&Pl[wv][(mi * 16 + lo) * 72 + nj * 16 + hi * 4] = pk;
            }
        }

        #pragma unroll
        for (int ks = 0; ks < 2; ++ks) {
            bf16x8 pa[2];
            #pragma unroll
            for (int mi = 0; mi < 2; ++mi)
                pa[mi] = *(const bf16x8*)&Pl[wv][(mi * 16 + lo) * 72 + ks * 32 + hi * 8];
            bf16x8 vb[4];
            #pragma unroll
            for (int dj = 0; dj < 4; ++dj) {
                const int d = dj * 16 + lo, c = ks * 4 + hi;
                vb[dj] = *(const bf16x8*)&Vl[cur][d * 64 + ((c ^ (d & 7)) * 8)];
            }
            __builtin_amdgcn_s_setprio(1);
            #pragma unroll
            for (int mi = 0; mi < 2; ++mi)
                #pragma unroll
                for (int dj = 0; dj < 4; ++dj)
                    o[mi][dj] = MFMA_BF16(pa[mi], vb[dj], o[mi][dj]);
            __builtin_amdgcn_s_setprio(0);
        }
        __syncthreads();
    }

    #pragma unroll
    for (int mi = 0; mi < 2; ++mi) {
        float l = lp[mi];
        l += __shfl_xor(l, 16);
        l += __shfl_xor(l, 32);
        #pragma unroll
        for (int r = 0; r < 4; ++r) {
            const float lr = __shfl(l, hi * 4 + r, 16);
            const float rcp = 1.0f / lr;
            const int srow = qrow0 + mi * 16 + hi * 4 + r;
            #pragma unroll
            for (int dj = 0; dj < 4; ++dj)
                AO[((size_t)(b * 1024 + srow)) * 768 + h * 64 + dj * 16 + lo] =
                    f2bf(o[mi][dj][r] * rcp);
        }
    }
}

// ---------------- GEMM2: 128x128xBK64, 2-buf counted vmcnt; fp32 out + bias ----------------
__global__ __launch_bounds__(256) void gemm_out_mfma(
    const ushort* __restrict__ A, const ushort* __restrict__ Bt,
    const float* __restrict__ bias, float* __restrict__ C)
{
    __shared__ ushort Al[2][8192];
    __shared__ ushort Bl[2][8192];
    const int tid = threadIdx.x, lane = tid & 63;
    const int wv = tid >> 6, lo = lane & 15, hi = lane >> 4;
    const int wr = wv >> 1, wc = wv & 1;
    const int L = blockIdx.x;
    const int nid = (L & 7) * 48 + (L >> 3);    // bijective: 384 % 8 == 0
    const int n0 = (nid % 6) * 128, m0 = (nid / 6) * 128;

    auto stage = [&](int bi, int k0) {
        #pragma unroll
        for (int it = 0; it < 4; ++it) {
            const int p = it * 256 + tid;
            const int row = p >> 3, ch = (p & 7) ^ (row & 7);
            GLDS16(A + (size_t)(m0 + row) * 768 + k0 + ch * 8,
                   &Al[bi][(it * 256 + (tid & 192)) * 8]);
        }
        #pragma unroll
        for (int it = 0; it < 4; ++it) {
            const int p = it * 256 + tid;
            const int row = p >> 3, ch = (p & 7) ^ (row & 7);
            GLDS16(Bt + (size_t)(n0 + row) * 768 + k0 + ch * 8,
                   &Bl[bi][(it * 256 + (tid & 192)) * 8]);
        }
    };

    f32x4 acc[4][4];
    #pragma unroll
    for (int i = 0; i < 4; ++i)
        #pragma unroll
        for (int j = 0; j < 4; ++j)
            acc[i][j] = (f32x4){0.f, 0.f, 0.f, 0.f};

    stage(0, 0);
    stage(1, 64);

    int cur = 0;
    for (int t = 0; t < 12; ++t) {
        if (t < 11) asm volatile("s_waitcnt vmcnt(8)" ::: "memory");
        else        asm volatile("s_waitcnt vmcnt(0)" ::: "memory");
        __builtin_amdgcn_s_barrier();
        asm volatile("" ::: "memory");

        #pragma unroll
        for (int ks = 0; ks < 2; ++ks) {
            bf16x8 af[4], bfr[4];
            #pragma unroll
            for (int i = 0; i < 4; ++i) {
                const int ra = wr * 64 + i * 16 + lo;
                af[i] = *(const bf16x8*)&Al[cur][ra * 64 + (((ks * 4 + hi) ^ (ra & 7)) * 8)];
                const int rb = wc * 64 + i * 16 + lo;
                bfr[i] = *(const bf16x8*)&Bl[cur][rb * 64 + (((ks * 4 + hi) ^ (rb & 7)) * 8)];
            }
            #pragma unroll
            for (int mi = 0; mi < 4; ++mi)
                #pragma unroll
                for (int nj = 0; nj < 4; ++nj)
                    acc[mi][nj] = MFMA_BF16(bfr[nj], af[mi], acc[mi][nj]);
        }

        asm volatile("s_waitcnt lgkmcnt(0)" ::: "memory");
        __builtin_amdgcn_s_barrier();
        asm volatile("" ::: "memory");
        if (t + 2 < 12) stage(cur, (t + 2) * 64);
        cur ^= 1;
    }

    const int ncol0 = n0 + wc * 64;
    #pragma unroll
    for (int mi = 0; mi < 4; ++mi) {
        const int m = m0 + wr * 64 + mi * 16 + lo;
        #pragma unroll
        for (int nj = 0; nj < 4; ++nj) {
            const int nb = ncol0 + nj * 16 + hi * 4;
            const float4 bv = *reinterpret_cast<const float4*>(&bias[nb]);
            float4 ov;
            ov.x = acc[mi][nj][0] + bv.x; ov.y = acc[mi][nj][1] + bv.y;
            ov.z = acc[mi][nj][2] + bv.z; ov.w = acc[mi][nj][3] + bv.w;
            *reinterpret_cast<float4*>(&C[(size_t)m * 768 + nb]) = ov;
        }
    }
}

extern "C" void kernel_launch(void* const* d_in, const int* in_sizes, int n_in,
                              void* d_out, int out_size, void* d_ws, size_t ws_size,
                              hipStream_t stream) {
    const float* x     = (const float*)d_in[0];
    const float* w_qkv = (const float*)d_in[1];
    const float* w_out = (const float*)d_in[2];
    const float* b_out = (const float*)d_in[3];
    float* out = (float*)d_out;

    (void)in_sizes; (void)n_in; (void)out_size; (void)ws_size;

    ushort* xb   = (ushort*)d_ws;            // 6291456  (x bf16)
    ushort* wqbt = xb + 6291456;             // 1769472  (w_qkv^T bf16 [2304][768])
    ushort* wobt = wqbt + 1769472;           // 589824   (w_out^T bf16 [768][768])
    ushort* Qs   = wobt + 589824;            // 6291456  (Q*0.125*log2e, [B,H,S,D])
    ushort* Ks   = Qs + 6291456;             // 6291456  ([B,H,S,D])
    ushort* Vt   = Ks + 6291456;             // 6291456  ([B,H,D,S])
    ushort* AO   = Vt + 6291456;             // 6291456  ([B,S,E] bf16)

    prep_kernel<<<4352, 256, 0, stream>>>(x, w_qkv, w_out, xb, wqbt, wobt);
    gemm_qkv_mfma<<<288, 512, 0, stream>>>(xb, wqbt, Qs, Ks, Vt);
    attn_mfma_kernel<<<768, 256, 0, stream>>>(Qs, Ks, Vt, AO);
    gemm_out_mfma<<<384, 256, 0, stream>>>(AO, wobt, b_out, out);
}

// Round 9
// 163.627 us; speedup vs baseline: 1.1417x; 1.1417x over previous
//
#include <hip/hip_runtime.h>

typedef float f32x4 __attribute__((ext_vector_type(4)));
typedef short bf16x8 __attribute__((ext_vector_type(8)));

#define MFMA_BF16(a, b, c) __builtin_amdgcn_mfma_f32_16x16x32_bf16((a), (b), (c), 0, 0, 0)

#define GLDS16(gp, lp) __builtin_amdgcn_global_load_lds( \
    (const __attribute__((address_space(1))) unsigned int*)(gp), \
    (__attribute__((address_space(3))) unsigned int*)(lp), 16, 0, 0)

__device__ __forceinline__ ushort f2bf(float f) {
    unsigned int u = __float_as_uint(f);
    return (ushort)((u + 0x7FFFu + ((u >> 16) & 1u)) >> 16);
}

__device__ __forceinline__ float fexp2(float x) {
#if __has_builtin(__builtin_amdgcn_exp2f)
    return __builtin_amdgcn_exp2f(x);
#else
    return exp2f(x);
#endif
}

// ---------------- prep: cvt x + transpose/cvt both weight matrices ----------------
__global__ __launch_bounds__(256) void prep_kernel(
    const float* __restrict__ x, const float* __restrict__ wq, const float* __restrict__ wo,
    ushort* __restrict__ xb, ushort* __restrict__ wqbt, ushort* __restrict__ wobt)
{
    __shared__ float tile[32][33];
    const int bid = blockIdx.x;
    if (bid < 2048) {
        const float4* src = (const float4*)x;
        ushort4* dst = (ushort4*)xb;
        for (int i = bid * 256 + threadIdx.x; i < 1572864; i += 2048 * 256) {
            float4 v = src[i];
            ushort4 o;
            o.x = f2bf(v.x); o.y = f2bf(v.y); o.z = f2bf(v.z); o.w = f2bf(v.w);
            dst[i] = o;
        }
        return;
    }
    const float* src; ushort* dst; int K, N, bx, by;
    if (bid < 3776) {
        const int L = bid - 2048;
        src = wq; dst = wqbt; K = 768; N = 2304; bx = L % 72; by = L / 72;
    } else {
        const int L = bid - 3776;
        src = wo; dst = wobt; K = 768; N = 768; bx = L % 24; by = L / 24;
    }
    const int n0 = bx * 32, k0 = by * 32;
    const int c = threadIdx.x & 31, rb = threadIdx.x >> 5;
    #pragma unroll
    for (int i = 0; i < 4; ++i)
        tile[i * 8 + rb][c] = src[(size_t)(k0 + i * 8 + rb) * N + n0 + c];
    __syncthreads();
    #pragma unroll
    for (int i = 0; i < 4; ++i) {
        int nr = i * 8 + rb;
        dst[(size_t)(n0 + nr) * K + k0 + c] = f2bf(tile[c][nr]);
    }
}

// ---------------- GEMM1: persistent blocks, 3 n-tiles/block, 128x128xBK64, counted vmcnt ----------------
// grid 384 (xcd-swizzled, all resident -> no tail), block 256, 64KB LDS (2 blocks/CU).
__global__ __launch_bounds__(256) void gemm_qkv_mfma(
    const ushort* __restrict__ A, const ushort* __restrict__ Bt,
    ushort* __restrict__ Qo, ushort* __restrict__ Ko, ushort* __restrict__ Vo)
{
    __shared__ ushort Al[2][8192];   // 2 x 128x64 bf16 = 32 KiB
    __shared__ ushort Bl[2][8192];   // 32 KiB
    const int tid = threadIdx.x, lane = tid & 63;
    const int wv = tid >> 6, lo = lane & 15, hi = lane >> 4;
    const int wr = wv >> 1, wc = wv & 1;
    const int L = blockIdx.x;
    const int nid = (L & 7) * 48 + (L >> 3);    // bijective: 384 % 8 == 0
    const int m0 = (nid / 6) * 128;
    const int ngrp = nid % 6;                   // 3 n-tiles: ngrp*3 .. ngrp*3+2
    const int region = ngrp >> 1;               // 0:Q 1:K 2:V (uniform per block)

    // flat step s = g*12 + khat over 36 K-tiles
    auto stage = [&](int bi, int s) {
        const int k0 = (s % 12) * 64;
        const int n0 = (ngrp * 3 + s / 12) * 128;
        #pragma unroll
        for (int it = 0; it < 4; ++it) {
            const int p = it * 256 + tid;             // 1024 chunks of 16B
            const int row = p >> 3, ch = (p & 7) ^ (row & 7);
            GLDS16(A + (size_t)(m0 + row) * 768 + k0 + ch * 8,
                   &Al[bi][(it * 256 + (tid & 192)) * 8]);
        }
        #pragma unroll
        for (int it = 0; it < 4; ++it) {
            const int p = it * 256 + tid;
            const int row = p >> 3, ch = (p & 7) ^ (row & 7);
            GLDS16(Bt + (size_t)(n0 + row) * 768 + k0 + ch * 8,
                   &Bl[bi][(it * 256 + (tid & 192)) * 8]);
        }
    };

    f32x4 acc[4][4];
    #pragma unroll
    for (int i = 0; i < 4; ++i)
        #pragma unroll
        for (int j = 0; j < 4; ++j)
            acc[i][j] = (f32x4){0.f, 0.f, 0.f, 0.f};

    stage(0, 0);
    stage(1, 1);

    int cur = 0;
    for (int s = 0; s < 36; ++s) {
        // step s's loads (oldest 8) landed; step s+1's stay in flight across barrier.
        // (after a tile-boundary epilogue, the queue also holds its stores — they age
        //  a full iteration before this wait, so no stall)
        if (s < 35) asm volatile("s_waitcnt vmcnt(8)" ::: "memory");
        else        asm volatile("s_waitcnt vmcnt(0)" ::: "memory");
        __builtin_amdgcn_s_barrier();
        asm volatile("" ::: "memory");

        #pragma unroll
        for (int ks = 0; ks < 2; ++ks) {
            bf16x8 af[4], bfr[4];
            #pragma unroll
            for (int i = 0; i < 4; ++i) {
                const int ra = wr * 64 + i * 16 + lo;
                af[i] = *(const bf16x8*)&Al[cur][ra * 64 + (((ks * 4 + hi) ^ (ra & 7)) * 8)];
                const int rb = wc * 64 + i * 16 + lo;
                bfr[i] = *(const bf16x8*)&Bl[cur][rb * 64 + (((ks * 4 + hi) ^ (rb & 7)) * 8)];
            }
            if (region == 2) {
                #pragma unroll
                for (int mi = 0; mi < 4; ++mi)
                    #pragma unroll
                    for (int nj = 0; nj < 4; ++nj)
                        acc[mi][nj] = MFMA_BF16(af[mi], bfr[nj], acc[mi][nj]);
            } else {
                #pragma unroll
                for (int mi = 0; mi < 4; ++mi)
                    #pragma unroll
                    for (int nj = 0; nj < 4; ++nj)
                        acc[mi][nj] = MFMA_BF16(bfr[nj], af[mi], acc[mi][nj]);
            }
        }

        asm volatile("s_waitcnt lgkmcnt(0)" ::: "memory");
        __builtin_amdgcn_s_barrier();            // all waves done reading buf[cur]
        asm volatile("" ::: "memory");

        if ((s % 12) == 11) {
            // tile-boundary epilogue for g = s/12 (stores enter vmcnt queue BEFORE next stage)
            const int n0g = (ngrp * 3 + s / 12) * 128;
            const int h = ((n0g % 768) >> 6) + wc;
            if (region == 2) {
                #pragma unroll
                for (int mi = 0; mi < 4; ++mi) {
                    const int m4 = m0 + wr * 64 + mi * 16 + hi * 4;
                    const int b = m4 >> 10, sx = m4 & 1023;
                    #pragma unroll
                    for (int nj = 0; nj < 4; ++nj) {
                        const int d = nj * 16 + lo;
                        ushort4 pk;
                        pk.x = f2bf(acc[mi][nj][0]); pk.y = f2bf(acc[mi][nj][1]);
                        pk.z = f2bf(acc[mi][nj][2]); pk.w = f2bf(acc[mi][nj][3]);
                        *(ushort4*)&Vo[((size_t)(b * 12 + h) * 64 + d) * 1024 + sx] = pk;
                    }
                }
            } else {
                ushort* dst = region ? Ko : Qo;
                const float sc = region ? 1.0f : 0.18033688011112042f;  // (1/8)*log2(e) for Q
                #pragma unroll
                for (int mi = 0; mi < 4; ++mi) {
                    const int s_idx = m0 + wr * 64 + mi * 16 + lo;
                    const int b = s_idx >> 10, sx = s_idx & 1023;
                    const size_t base = ((size_t)(b * 12 + h) * 1024 + sx) * 64;
                    #pragma unroll
                    for (int nj = 0; nj < 4; ++nj) {
                        ushort4 pk;
                        pk.x = f2bf(acc[mi][nj][0] * sc); pk.y = f2bf(acc[mi][nj][1] * sc);
                        pk.z = f2bf(acc[mi][nj][2] * sc); pk.w = f2bf(acc[mi][nj][3] * sc);
                        *(ushort4*)&dst[base + nj * 16 + hi * 4] = pk;
                    }
                }
            }
            #pragma unroll
            for (int i = 0; i < 4; ++i)
                #pragma unroll
                for (int j = 0; j < 4; ++j)
                    acc[i][j] = (f32x4){0.f, 0.f, 0.f, 0.f};
        }

        if (s + 2 < 36) stage(cur, s + 2);       // overwrite freed buffer
        cur ^= 1;
    }
}

// ---------------- Flash attention, bf16 MFMA, no-max softmax, S^T trick, setprio ----------------
__global__ __launch_bounds__(256) void attn_mfma_kernel(
    const ushort* __restrict__ Qg, const ushort* __restrict__ Kg,
    const ushort* __restrict__ Vg, ushort* __restrict__ AO)
{
    __shared__ ushort Kl[2][4096];
    __shared__ ushort Vl[2][4096];
    __shared__ ushort Pl[4][32 * 72];

    const int tid = threadIdx.x, lane = tid & 63;
    const int wv = tid >> 6, lo = lane & 15, hi = lane >> 4;
    const int L = blockIdx.x;
    const int xcd = L & 7, g = L >> 3;
    const int qb = g / 12;
    const int bh = xcd * 12 + (g % 12);
    const int b = bh / 12, h = bh % 12;
    const size_t kvbase = (size_t)bh * (1024 * 64);

    bf16x8 qa[2][2];
    const int qrow0 = qb * 128 + wv * 32;
    #pragma unroll
    for (int mi = 0; mi < 2; ++mi)
        #pragma unroll
        for (int ks = 0; ks < 2; ++ks)
            qa[mi][ks] = *(const bf16x8*)&Qg[kvbase + (size_t)(qrow0 + mi * 16 + lo) * 64 + ks * 32 + hi * 8];

    f32x4 o[2][4];
    float lp[2] = {0.f, 0.f};
    #pragma unroll
    for (int mi = 0; mi < 2; ++mi)
        #pragma unroll
        for (int dj = 0; dj < 4; ++dj) o[mi][dj] = (f32x4){0.f, 0.f, 0.f, 0.f};

    auto stage = [&](int bi, int kt) {
        #pragma unroll
        for (int it = 0; it < 2; ++it) {
            const int p = it * 256 + tid;
            const int row = p >> 3, ch = (p & 7) ^ (row & 7);
            GLDS16(Kg + kvbase + (size_t)(kt + row) * 64 + ch * 8, &Kl[bi][(it * 256 + (tid & 192)) * 8]);
        }
        #pragma unroll
        for (int it = 0; it < 2; ++it) {
            const int p = it * 256 + tid;
            const int row = p >> 3, ch = (p & 7) ^ (row & 7);
            GLDS16(Vg + kvbase + (size_t)row * 1024 + kt + ch * 8, &Vl[bi][(it * 256 + (tid & 192)) * 8]);
        }
    };

    stage(0, 0);
    __syncthreads();

    for (int t = 0; t < 16; ++t) {
        const int cur = t & 1;
        if (t < 15) stage(cur ^ 1, (t + 1) * 64);

        f32x4 s[2][4];
        #pragma unroll
        for (int mi = 0; mi < 2; ++mi)
            #pragma unroll
            for (int nj = 0; nj < 4; ++nj) s[mi][nj] = (f32x4){0.f, 0.f, 0.f, 0.f};
        #pragma unroll
        for (int ks = 0; ks < 2; ++ks) {
            bf16x8 kb[4];
            #pragma unroll
            for (int nj = 0; nj < 4; ++nj) {
                const int key = nj * 16 + lo, c = ks * 4 + hi;
                kb[nj] = *(const bf16x8*)&Kl[cur][key * 64 + ((c ^ (key & 7)) * 8)];
            }
            __builtin_amdgcn_s_setprio(1);
            #pragma unroll
            for (int mi = 0; mi < 2; ++mi)
                #pragma unroll
                for (int nj = 0; nj < 4; ++nj)
                    s[mi][nj] = MFMA_BF16(kb[nj], qa[mi][ks], s[mi][nj]);
            __builtin_amdgcn_s_setprio(0);
        }

        #pragma unroll
        for (int mi = 0; mi < 2; ++mi) {
            #pragma unroll
            for (int nj = 0; nj < 4; ++nj) {
                const unsigned int u0 = __float_as_uint(fexp2(s[mi][nj][0]));
                const unsigned int u1 = __float_as_uint(fexp2(s[mi][nj][1]));
                const unsigned int u2 = __float_as_uint(fexp2(s[mi][nj][2]));
                const unsigned int u3 = __float_as_uint(fexp2(s[mi][nj][3]));
                const float t0 = __uint_as_float(u0 & 0xFFFF0000u);
                const float t1 = __uint_as_float(u1 & 0xFFFF0000u);
                const float t2 = __uint_as_float(u2 & 0xFFFF0000u);
                const float t3 = __uint_as_float(u3 & 0xFFFF0000u);
                lp[mi] += (t0 + t1) + (t2 + t3);
                ushort4 pk;
                pk.x = (ushort)(u0 >> 16); pk.y = (ushort)(u1 >> 16);
                pk.z = (ushort)(u2 >> 16); pk.w = (ushort)(u3 >> 16);
                *(ushort4*)&Pl[wv][(mi * 16 + lo) * 72 + nj * 16 + hi * 4] = pk;
            }
        }

        #pragma unroll
        for (int ks = 0; ks < 2; ++ks) {
            bf16x8 pa[2];
            #pragma unroll
            for (int mi = 0; mi < 2; ++mi)
                pa[mi] = *(const bf16x8*)&Pl[wv][(mi * 16 + lo) * 72 + ks * 32 + hi * 8];
            bf16x8 vb[4];
            #pragma unroll
            for (int dj = 0; dj < 4; ++dj) {
                const int d = dj * 16 + lo, c = ks * 4 + hi;
                vb[dj] = *(const bf16x8*)&Vl[cur][d * 64 + ((c ^ (d & 7)) * 8)];
            }
            __builtin_amdgcn_s_setprio(1);
            #pragma unroll
            for (int mi = 0; mi < 2; ++mi)
                #pragma unroll
                for (int dj = 0; dj < 4; ++dj)
                    o[mi][dj] = MFMA_BF16(pa[mi], vb[dj], o[mi][dj]);
            __builtin_amdgcn_s_setprio(0);
        }
        __syncthreads();
    }

    #pragma unroll
    for (int mi = 0; mi < 2; ++mi) {
        float l = lp[mi];
        l += __shfl_xor(l, 16);
        l += __shfl_xor(l, 32);
        #pragma unroll
        for (int r = 0; r < 4; ++r) {
            const float lr = __shfl(l, hi * 4 + r, 16);
            const float rcp = 1.0f / lr;
            const int srow = qrow0 + mi * 16 + hi * 4 + r;
            #pragma unroll
            for (int dj = 0; dj < 4; ++dj)
                AO[((size_t)(b * 1024 + srow)) * 768 + h * 64 + dj * 16 + lo] =
                    f2bf(o[mi][dj][r] * rcp);
        }
    }
}

// ---------------- GEMM2: 128x128xBK64, 2-buf counted vmcnt; fp32 out + bias ----------------
__global__ __launch_bounds__(256) void gemm_out_mfma(
    const ushort* __restrict__ A, const ushort* __restrict__ Bt,
    const float* __restrict__ bias, float* __restrict__ C)
{
    __shared__ ushort Al[2][8192];
    __shared__ ushort Bl[2][8192];
    const int tid = threadIdx.x, lane = tid & 63;
    const int wv = tid >> 6, lo = lane & 15, hi = lane >> 4;
    const int wr = wv >> 1, wc = wv & 1;
    const int L = blockIdx.x;
    const int nid = (L & 7) * 48 + (L >> 3);    // bijective: 384 % 8 == 0
    const int n0 = (nid % 6) * 128, m0 = (nid / 6) * 128;

    auto stage = [&](int bi, int k0) {
        #pragma unroll
        for (int it = 0; it < 4; ++it) {
            const int p = it * 256 + tid;
            const int row = p >> 3, ch = (p & 7) ^ (row & 7);
            GLDS16(A + (size_t)(m0 + row) * 768 + k0 + ch * 8,
                   &Al[bi][(it * 256 + (tid & 192)) * 8]);
        }
        #pragma unroll
        for (int it = 0; it < 4; ++it) {
            const int p = it * 256 + tid;
            const int row = p >> 3, ch = (p & 7) ^ (row & 7);
            GLDS16(Bt + (size_t)(n0 + row) * 768 + k0 + ch * 8,
                   &Bl[bi][(it * 256 + (tid & 192)) * 8]);
        }
    };

    f32x4 acc[4][4];
    #pragma unroll
    for (int i = 0; i < 4; ++i)
        #pragma unroll
        for (int j = 0; j < 4; ++j)
            acc[i][j] = (f32x4){0.f, 0.f, 0.f, 0.f};

    stage(0, 0);
    stage(1, 64);

    int cur = 0;
    for (int t = 0; t < 12; ++t) {
        if (t < 11) asm volatile("s_waitcnt vmcnt(8)" ::: "memory");
        else        asm volatile("s_waitcnt vmcnt(0)" ::: "memory");
        __builtin_amdgcn_s_barrier();
        asm volatile("" ::: "memory");

        #pragma unroll
        for (int ks = 0; ks < 2; ++ks) {
            bf16x8 af[4], bfr[4];
            #pragma unroll
            for (int i = 0; i < 4; ++i) {
                const int ra = wr * 64 + i * 16 + lo;
                af[i] = *(const bf16x8*)&Al[cur][ra * 64 + (((ks * 4 + hi) ^ (ra & 7)) * 8)];
                const int rb = wc * 64 + i * 16 + lo;
                bfr[i] = *(const bf16x8*)&Bl[cur][rb * 64 + (((ks * 4 + hi) ^ (rb & 7)) * 8)];
            }
            #pragma unroll
            for (int mi = 0; mi < 4; ++mi)
                #pragma unroll
                for (int nj = 0; nj < 4; ++nj)
                    acc[mi][nj] = MFMA_BF16(bfr[nj], af[mi], acc[mi][nj]);
        }

        asm volatile("s_waitcnt lgkmcnt(0)" ::: "memory");
        __builtin_amdgcn_s_barrier();
        asm volatile("" ::: "memory");
        if (t + 2 < 12) stage(cur, (t + 2) * 64);
        cur ^= 1;
    }

    const int ncol0 = n0 + wc * 64;
    #pragma unroll
    for (int mi = 0; mi < 4; ++mi) {
        const int m = m0 + wr * 64 + mi * 16 + lo;
        #pragma unroll
        for (int nj = 0; nj < 4; ++nj) {
            const int nb = ncol0 + nj * 16 + hi * 4;
            const float4 bv = *reinterpret_cast<const float4*>(&bias[nb]);
            float4 ov;
            ov.x = acc[mi][nj][0] + bv.x; ov.y = acc[mi][nj][1] + bv.y;
            ov.z = acc[mi][nj][2] + bv.z; ov.w = acc[mi][nj][3] + bv.w;
            *reinterpret_cast<float4*>(&C[(size_t)m * 768 + nb]) = ov;
        }
    }
}

extern "C" void kernel_launch(void* const* d_in, const int* in_sizes, int n_in,
                              void* d_out, int out_size, void* d_ws, size_t ws_size,
                              hipStream_t stream) {
    const float* x     = (const float*)d_in[0];
    const float* w_qkv = (const float*)d_in[1];
    const float* w_out = (const float*)d_in[2];
    const float* b_out = (const float*)d_in[3];
    float* out = (float*)d_out;

    (void)in_sizes; (void)n_in; (void)out_size; (void)ws_size;

    ushort* xb   = (ushort*)d_ws;            // 6291456  (x bf16)
    ushort* wqbt = xb + 6291456;             // 1769472  (w_qkv^T bf16 [2304][768])
    ushort* wobt = wqbt + 1769472;           // 589824   (w_out^T bf16 [768][768])
    ushort* Qs   = wobt + 589824;            // 6291456  (Q*0.125*log2e, [B,H,S,D])
    ushort* Ks   = Qs + 6291456;             // 6291456  ([B,H,S,D])
    ushort* Vt   = Ks + 6291456;             // 6291456  ([B,H,D,S])
    ushort* AO   = Vt + 6291456;             // 6291456  ([B,S,E] bf16)

    prep_kernel<<<4352, 256, 0, stream>>>(x, w_qkv, w_out, xb, wqbt, wobt);
    gemm_qkv_mfma<<<384, 256, 0, stream>>>(xb, wqbt, Qs, Ks, Vt);
    attn_mfma_kernel<<<768, 256, 0, stream>>>(Qs, Ks, Vt, AO);
    gemm_out_mfma<<<384, 256, 0, stream>>>(AO, wobt, b_out, out);
}

// Round 10
// 145.091 us; speedup vs baseline: 1.2875x; 1.1278x over previous
//
#include <hip/hip_runtime.h>

typedef float f32x4 __attribute__((ext_vector_type(4)));
typedef short bf16x8 __attribute__((ext_vector_type(8)));

#define MFMA_BF16(a, b, c) __builtin_amdgcn_mfma_f32_16x16x32_bf16((a), (b), (c), 0, 0, 0)

#define GLDS16(gp, lp) __builtin_amdgcn_global_load_lds( \
    (const __attribute__((address_space(1))) unsigned int*)(gp), \
    (__attribute__((address_space(3))) unsigned int*)(lp), 16, 0, 0)

__device__ __forceinline__ ushort f2bf(float f) {
    unsigned int u = __float_as_uint(f);
    return (ushort)((u + 0x7FFFu + ((u >> 16) & 1u)) >> 16);
}

__device__ __forceinline__ float fexp2(float x) {
#if __has_builtin(__builtin_amdgcn_exp2f)
    return __builtin_amdgcn_exp2f(x);
#else
    return exp2f(x);
#endif
}

// ---------------- prep: cvt x + transpose/cvt both weight matrices ----------------
__global__ __launch_bounds__(256) void prep_kernel(
    const float* __restrict__ x, const float* __restrict__ wq, const float* __restrict__ wo,
    ushort* __restrict__ xb, ushort* __restrict__ wqbt, ushort* __restrict__ wobt)
{
    __shared__ float tile[32][33];
    const int bid = blockIdx.x;
    if (bid < 2048) {
        const float4* src = (const float4*)x;
        ushort4* dst = (ushort4*)xb;
        for (int i = bid * 256 + threadIdx.x; i < 1572864; i += 2048 * 256) {
            float4 v = src[i];
            ushort4 o;
            o.x = f2bf(v.x); o.y = f2bf(v.y); o.z = f2bf(v.z); o.w = f2bf(v.w);
            dst[i] = o;
        }
        return;
    }
    const float* src; ushort* dst; int K, N, bx, by;
    if (bid < 3776) {
        const int L = bid - 2048;
        src = wq; dst = wqbt; K = 768; N = 2304; bx = L % 72; by = L / 72;
    } else {
        const int L = bid - 3776;
        src = wo; dst = wobt; K = 768; N = 768; bx = L % 24; by = L / 24;
    }
    const int n0 = bx * 32, k0 = by * 32;
    const int c = threadIdx.x & 31, rb = threadIdx.x >> 5;
    #pragma unroll
    for (int i = 0; i < 4; ++i)
        tile[i * 8 + rb][c] = src[(size_t)(k0 + i * 8 + rb) * N + n0 + c];
    __syncthreads();
    #pragma unroll
    for (int i = 0; i < 4; ++i) {
        int nr = i * 8 + rb;
        dst[(size_t)(n0 + nr) * K + k0 + c] = f2bf(tile[c][nr]);
    }
}

// ---------------- GEMM1: 128x128xBK32, 3-buf, SINGLE barrier/step, counted vmcnt ----------------
// grid 1152 (xcd-swizzled), block 256, 48KB LDS -> 3 blocks/CU.
__global__ __launch_bounds__(256) void gemm_qkv_mfma(
    const ushort* __restrict__ A, const ushort* __restrict__ Bt,
    ushort* __restrict__ Qo, ushort* __restrict__ Ko, ushort* __restrict__ Vo)
{
    __shared__ ushort Al[3][4096];   // 3 x 128x32 bf16 = 24 KiB
    __shared__ ushort Bl[3][4096];   // 24 KiB
    const int tid = threadIdx.x, lane = tid & 63;
    const int wv = tid >> 6, lo = lane & 15, hi = lane >> 4;
    const int wr = wv >> 1, wc = wv & 1;
    const int L = blockIdx.x;
    const int nid = (L & 7) * 144 + (L >> 3);   // bijective: 1152 % 8 == 0
    const int n0 = (nid % 18) * 128, m0 = (nid / 18) * 128;

    // 128x32 bf16 tile = 512 x 16B chunks; 2 GLDS/thread per matrix
    auto stage = [&](int bi, int s) {
        const int k0 = s * 32;
        #pragma unroll
        for (int it = 0; it < 2; ++it) {
            const int p = it * 256 + tid;
            const int row = p >> 2, c = p & 3;
            GLDS16(A + (size_t)(m0 + row) * 768 + k0 + ((c ^ (row & 3)) * 8),
                   &Al[bi][(it * 256 + (tid & 192)) * 8]);
        }
        #pragma unroll
        for (int it = 0; it < 2; ++it) {
            const int p = it * 256 + tid;
            const int row = p >> 2, c = p & 3;
            GLDS16(Bt + (size_t)(n0 + row) * 768 + k0 + ((c ^ (row & 3)) * 8),
                   &Bl[bi][(it * 256 + (tid & 192)) * 8]);
        }
    };

    f32x4 acc[4][4];
    #pragma unroll
    for (int i = 0; i < 4; ++i)
        #pragma unroll
        for (int j = 0; j < 4; ++j)
            acc[i][j] = (f32x4){0.f, 0.f, 0.f, 0.f};

    const int region = n0 / 768;                 // 0:Q 1:K 2:V (uniform per block)
    const int h = ((n0 % 768) >> 6) + wc;

    stage(0, 0);
    stage(1, 1);

    int cur = 0;
    for (int s = 0; s < 24; ++s) {
        // step s's 4 loads (oldest) landed; step s+1's stay in flight across barrier
        if (s < 23) asm volatile("s_waitcnt vmcnt(4)" ::: "memory");
        else        asm volatile("s_waitcnt vmcnt(0)" ::: "memory");
        __builtin_amdgcn_s_barrier();
        asm volatile("" ::: "memory");
        // all waves finished reading buf[s%3] for step s-1..; staging (s+2)%3 is safe:
        // it only aliases the buffer whose reads completed before this barrier.
        if (s + 2 < 24) stage(cur == 0 ? 2 : cur - 1, s + 2);   // (s+2)%3

        bf16x8 af[4], bfr[4];
        #pragma unroll
        for (int i = 0; i < 4; ++i) {
            const int ra = wr * 64 + i * 16 + lo;
            af[i] = *(const bf16x8*)&Al[cur][ra * 32 + ((hi ^ (ra & 3)) * 8)];
            const int rb = wc * 64 + i * 16 + lo;
            bfr[i] = *(const bf16x8*)&Bl[cur][rb * 32 + ((hi ^ (rb & 3)) * 8)];
        }
        if (region == 2) {
            #pragma unroll
            for (int mi = 0; mi < 4; ++mi)
                #pragma unroll
                for (int nj = 0; nj < 4; ++nj)
                    acc[mi][nj] = MFMA_BF16(af[mi], bfr[nj], acc[mi][nj]);
        } else {
            #pragma unroll
            for (int mi = 0; mi < 4; ++mi)
                #pragma unroll
                for (int nj = 0; nj < 4; ++nj)
                    acc[mi][nj] = MFMA_BF16(bfr[nj], af[mi], acc[mi][nj]);
        }
        cur = (cur == 2) ? 0 : cur + 1;
    }

    if (region == 2) {
        // natural: reg r -> s-row; ushort4 along s into V^T [d][s]
        #pragma unroll
        for (int mi = 0; mi < 4; ++mi) {
            const int m4 = m0 + wr * 64 + mi * 16 + hi * 4;
            const int b = m4 >> 10, sx = m4 & 1023;
            #pragma unroll
            for (int nj = 0; nj < 4; ++nj) {
                const int d = nj * 16 + lo;
                ushort4 pk;
                pk.x = f2bf(acc[mi][nj][0]); pk.y = f2bf(acc[mi][nj][1]);
                pk.z = f2bf(acc[mi][nj][2]); pk.w = f2bf(acc[mi][nj][3]);
                *(ushort4*)&Vo[((size_t)(b * 12 + h) * 64 + d) * 1024 + sx] = pk;
            }
        }
    } else {
        // swapped: reg r -> d; ushort4 along d into [s][d]
        ushort* dst = region ? Ko : Qo;
        const float sc = region ? 1.0f : 0.18033688011112042f;  // (1/8)*log2(e) for Q
        #pragma unroll
        for (int mi = 0; mi < 4; ++mi) {
            const int s_idx = m0 + wr * 64 + mi * 16 + lo;
            const int b = s_idx >> 10, sx = s_idx & 1023;
            const size_t base = ((size_t)(b * 12 + h) * 1024 + sx) * 64;
            #pragma unroll
            for (int nj = 0; nj < 4; ++nj) {
                ushort4 pk;
                pk.x = f2bf(acc[mi][nj][0] * sc); pk.y = f2bf(acc[mi][nj][1] * sc);
                pk.z = f2bf(acc[mi][nj][2] * sc); pk.w = f2bf(acc[mi][nj][3] * sc);
                *(ushort4*)&dst[base + nj * 16 + hi * 4] = pk;
            }
        }
    }
}

// ---------------- Flash attention, bf16 MFMA, no-max softmax, S^T trick, setprio ----------------
__global__ __launch_bounds__(256) void attn_mfma_kernel(
    const ushort* __restrict__ Qg, const ushort* __restrict__ Kg,
    const ushort* __restrict__ Vg, ushort* __restrict__ AO)
{
    __shared__ ushort Kl[2][4096];
    __shared__ ushort Vl[2][4096];
    __shared__ ushort Pl[4][32 * 72];

    const int tid = threadIdx.x, lane = tid & 63;
    const int wv = tid >> 6, lo = lane & 15, hi = lane >> 4;
    const int L = blockIdx.x;
    const int xcd = L & 7, g = L >> 3;
    const int qb = g / 12;
    const int bh = xcd * 12 + (g % 12);
    const int b = bh / 12, h = bh % 12;
    const size_t kvbase = (size_t)bh * (1024 * 64);

    bf16x8 qa[2][2];
    const int qrow0 = qb * 128 + wv * 32;
    #pragma unroll
    for (int mi = 0; mi < 2; ++mi)
        #pragma unroll
        for (int ks = 0; ks < 2; ++ks)
            qa[mi][ks] = *(const bf16x8*)&Qg[kvbase + (size_t)(qrow0 + mi * 16 + lo) * 64 + ks * 32 + hi * 8];

    f32x4 o[2][4];
    float lp[2] = {0.f, 0.f};
    #pragma unroll
    for (int mi = 0; mi < 2; ++mi)
        #pragma unroll
        for (int dj = 0; dj < 4; ++dj) o[mi][dj] = (f32x4){0.f, 0.f, 0.f, 0.f};

    auto stage = [&](int bi, int kt) {
        #pragma unroll
        for (int it = 0; it < 2; ++it) {
            const int p = it * 256 + tid;
            const int row = p >> 3, ch = (p & 7) ^ (row & 7);
            GLDS16(Kg + kvbase + (size_t)(kt + row) * 64 + ch * 8, &Kl[bi][(it * 256 + (tid & 192)) * 8]);
        }
        #pragma unroll
        for (int it = 0; it < 2; ++it) {
            const int p = it * 256 + tid;
            const int row = p >> 3, ch = (p & 7) ^ (row & 7);
            GLDS16(Vg + kvbase + (size_t)row * 1024 + kt + ch * 8, &Vl[bi][(it * 256 + (tid & 192)) * 8]);
        }
    };

    stage(0, 0);
    __syncthreads();

    for (int t = 0; t < 16; ++t) {
        const int cur = t & 1;
        if (t < 15) stage(cur ^ 1, (t + 1) * 64);

        f32x4 s[2][4];
        #pragma unroll
        for (int mi = 0; mi < 2; ++mi)
            #pragma unroll
            for (int nj = 0; nj < 4; ++nj) s[mi][nj] = (f32x4){0.f, 0.f, 0.f, 0.f};
        #pragma unroll
        for (int ks = 0; ks < 2; ++ks) {
            bf16x8 kb[4];
            #pragma unroll
            for (int nj = 0; nj < 4; ++nj) {
                const int key = nj * 16 + lo, c = ks * 4 + hi;
                kb[nj] = *(const bf16x8*)&Kl[cur][key * 64 + ((c ^ (key & 7)) * 8)];
            }
            __builtin_amdgcn_s_setprio(1);
            #pragma unroll
            for (int mi = 0; mi < 2; ++mi)
                #pragma unroll
                for (int nj = 0; nj < 4; ++nj)
                    s[mi][nj] = MFMA_BF16(kb[nj], qa[mi][ks], s[mi][nj]);
            __builtin_amdgcn_s_setprio(0);
        }

        #pragma unroll
        for (int mi = 0; mi < 2; ++mi) {
            #pragma unroll
            for (int nj = 0; nj < 4; ++nj) {
                const unsigned int u0 = __float_as_uint(fexp2(s[mi][nj][0]));
                const unsigned int u1 = __float_as_uint(fexp2(s[mi][nj][1]));
                const unsigned int u2 = __float_as_uint(fexp2(s[mi][nj][2]));
                const unsigned int u3 = __float_as_uint(fexp2(s[mi][nj][3]));
                const float t0 = __uint_as_float(u0 & 0xFFFF0000u);
                const float t1 = __uint_as_float(u1 & 0xFFFF0000u);
                const float t2 = __uint_as_float(u2 & 0xFFFF0000u);
                const float t3 = __uint_as_float(u3 & 0xFFFF0000u);
                lp[mi] += (t0 + t1) + (t2 + t3);
                ushort4 pk;
                pk.x = (ushort)(u0 >> 16); pk.y = (ushort)(u1 >> 16);
                pk.z = (ushort)(u2 >> 16); pk.w = (ushort)(u3 >> 16);
                *(ushort4*)&Pl[wv][(mi * 16 + lo) * 72 + nj * 16 + hi * 4] = pk;
            }
        }

        #pragma unroll
        for (int ks = 0; ks < 2; ++ks) {
            bf16x8 pa[2];
            #pragma unroll
            for (int mi = 0; mi < 2; ++mi)
                pa[mi] = *(const bf16x8*)&Pl[wv][(mi * 16 + lo) * 72 + ks * 32 + hi * 8];
            bf16x8 vb[4];
            #pragma unroll
            for (int dj = 0; dj < 4; ++dj) {
                const int d = dj * 16 + lo, c = ks * 4 + hi;
                vb[dj] = *(const bf16x8*)&Vl[cur][d * 64 + ((c ^ (d & 7)) * 8)];
            }
            __builtin_amdgcn_s_setprio(1);
            #pragma unroll
            for (int mi = 0; mi < 2; ++mi)
                #pragma unroll
                for (int dj = 0; dj < 4; ++dj)
                    o[mi][dj] = MFMA_BF16(pa[mi], vb[dj], o[mi][dj]);
            __builtin_amdgcn_s_setprio(0);
        }
        __syncthreads();
    }

    #pragma unroll
    for (int mi = 0; mi < 2; ++mi) {
        float l = lp[mi];
        l += __shfl_xor(l, 16);
        l += __shfl_xor(l, 32);
        #pragma unroll
        for (int r = 0; r < 4; ++r) {
            const float lr = __shfl(l, hi * 4 + r, 16);
            const float rcp = 1.0f / lr;
            const int srow = qrow0 + mi * 16 + hi * 4 + r;
            #pragma unroll
            for (int dj = 0; dj < 4; ++dj)
                AO[((size_t)(b * 1024 + srow)) * 768 + h * 64 + dj * 16 + lo] =
                    f2bf(o[mi][dj][r] * rcp);
        }
    }
}

// ---------------- GEMM2: 128x128xBK32, 3-buf single-barrier counted vmcnt; fp32 out + bias ----------------
// grid 384 (xcd-swizzled), block 256, 48KB LDS.
__global__ __launch_bounds__(256) void gemm_out_mfma(
    const ushort* __restrict__ A, const ushort* __restrict__ Bt,
    const float* __restrict__ bias, float* __restrict__ C)
{
    __shared__ ushort Al[3][4096];
    __shared__ ushort Bl[3][4096];
    const int tid = threadIdx.x, lane = tid & 63;
    const int wv = tid >> 6, lo = lane & 15, hi = lane >> 4;
    const int wr = wv >> 1, wc = wv & 1;
    const int L = blockIdx.x;
    const int nid = (L & 7) * 48 + (L >> 3);    // bijective: 384 % 8 == 0
    const int n0 = (nid % 6) * 128, m0 = (nid / 6) * 128;

    auto stage = [&](int bi, int s) {
        const int k0 = s * 32;
        #pragma unroll
        for (int it = 0; it < 2; ++it) {
            const int p = it * 256 + tid;
            const int row = p >> 2, c = p & 3;
            GLDS16(A + (size_t)(m0 + row) * 768 + k0 + ((c ^ (row & 3)) * 8),
                   &Al[bi][(it * 256 + (tid & 192)) * 8]);
        }
        #pragma unroll
        for (int it = 0; it < 2; ++it) {
            const int p = it * 256 + tid;
            const int row = p >> 2, c = p & 3;
            GLDS16(Bt + (size_t)(n0 + row) * 768 + k0 + ((c ^ (row & 3)) * 8),
                   &Bl[bi][(it * 256 + (tid & 192)) * 8]);
        }
    };

    f32x4 acc[4][4];
    #pragma unroll
    for (int i = 0; i < 4; ++i)
        #pragma unroll
        for (int j = 0; j < 4; ++j)
            acc[i][j] = (f32x4){0.f, 0.f, 0.f, 0.f};

    stage(0, 0);
    stage(1, 1);

    int cur = 0;
    for (int s = 0; s < 24; ++s) {
        if (s < 23) asm volatile("s_waitcnt vmcnt(4)" ::: "memory");
        else        asm volatile("s_waitcnt vmcnt(0)" ::: "memory");
        __builtin_amdgcn_s_barrier();
        asm volatile("" ::: "memory");
        if (s + 2 < 24) stage(cur == 0 ? 2 : cur - 1, s + 2);

        bf16x8 af[4], bfr[4];
        #pragma unroll
        for (int i = 0; i < 4; ++i) {
            const int ra = wr * 64 + i * 16 + lo;
            af[i] = *(const bf16x8*)&Al[cur][ra * 32 + ((hi ^ (ra & 3)) * 8)];
            const int rb = wc * 64 + i * 16 + lo;
            bfr[i] = *(const bf16x8*)&Bl[cur][rb * 32 + ((hi ^ (rb & 3)) * 8)];
        }
        #pragma unroll
        for (int mi = 0; mi < 4; ++mi)
            #pragma unroll
            for (int nj = 0; nj < 4; ++nj)
                acc[mi][nj] = MFMA_BF16(bfr[nj], af[mi], acc[mi][nj]);
        cur = (cur == 2) ? 0 : cur + 1;
    }

    const int ncol0 = n0 + wc * 64;
    #pragma unroll
    for (int mi = 0; mi < 4; ++mi) {
        const int m = m0 + wr * 64 + mi * 16 + lo;
        #pragma unroll
        for (int nj = 0; nj < 4; ++nj) {
            const int nb = ncol0 + nj * 16 + hi * 4;
            const float4 bv = *reinterpret_cast<const float4*>(&bias[nb]);
            float4 ov;
            ov.x = acc[mi][nj][0] + bv.x; ov.y = acc[mi][nj][1] + bv.y;
            ov.z = acc[mi][nj][2] + bv.z; ov.w = acc[mi][nj][3] + bv.w;
            *reinterpret_cast<float4*>(&C[(size_t)m * 768 + nb]) = ov;
        }
    }
}

extern "C" void kernel_launch(void* const* d_in, const int* in_sizes, int n_in,
                              void* d_out, int out_size, void* d_ws, size_t ws_size,
                              hipStream_t stream) {
    const float* x     = (const float*)d_in[0];
    const float* w_qkv = (const float*)d_in[1];
    const float* w_out = (const float*)d_in[2];
    const float* b_out = (const float*)d_in[3];
    float* out = (float*)d_out;

    (void)in_sizes; (void)n_in; (void)out_size; (void)ws_size;

    ushort* xb   = (ushort*)d_ws;            // 6291456  (x bf16)
    ushort* wqbt = xb + 6291456;             // 1769472  (w_qkv^T bf16 [2304][768])
    ushort* wobt = wqbt + 1769472;           // 589824   (w_out^T bf16 [768][768])
    ushort* Qs   = wobt + 589824;            // 6291456  (Q*0.125*log2e, [B,H,S,D])
    ushort* Ks   = Qs + 6291456;             // 6291456  ([B,H,S,D])
    ushort* Vt   = Ks + 6291456;             // 6291456  ([B,H,D,S])
    ushort* AO   = Vt + 6291456;             // 6291456  ([B,S,E] bf16)

    prep_kernel<<<4352, 256, 0, stream>>>(x, w_qkv, w_out, xb, wqbt, wobt);
    gemm_qkv_mfma<<<1152, 256, 0, stream>>>(xb, wqbt, Qs, Ks, Vt);
    attn_mfma_kernel<<<768, 256, 0, stream>>>(Qs, Ks, Vt, AO);
    gemm_out_mfma<<<384, 256, 0, stream>>>(AO, wobt, b_out, out);
}

// Round 11
// 123.857 us; speedup vs baseline: 1.5083x; 1.1714x over previous
//
#include <hip/hip_runtime.h>

typedef float f32x4 __attribute__((ext_vector_type(4)));
typedef short bf16x8 __attribute__((ext_vector_type(8)));

#define MFMA_BF16(a, b, c) __builtin_amdgcn_mfma_f32_16x16x32_bf16((a), (b), (c), 0, 0, 0)

#define GLDS16(gp, lp) __builtin_amdgcn_global_load_lds( \
    (const __attribute__((address_space(1))) unsigned int*)(gp), \
    (__attribute__((address_space(3))) unsigned int*)(lp), 16, 0, 0)

__device__ __forceinline__ ushort f2bf(float f) {
    unsigned int u = __float_as_uint(f);
    return (ushort)((u + 0x7FFFu + ((u >> 16) & 1u)) >> 16);
}

__device__ __forceinline__ float fexp2(float x) {
#if __has_builtin(__builtin_amdgcn_exp2f)
    return __builtin_amdgcn_exp2f(x);
#else
    return exp2f(x);
#endif
}

// ---------------- prep: cvt x + transpose/cvt both weight matrices, one launch ----------------
__global__ __launch_bounds__(256) void prep_kernel(
    const float* __restrict__ x, const float* __restrict__ wq, const float* __restrict__ wo,
    ushort* __restrict__ xb, ushort* __restrict__ wqbt, ushort* __restrict__ wobt)
{
    __shared__ float tile[32][33];
    const int bid = blockIdx.x;
    if (bid < 2048) {
        const float4* src = (const float4*)x;
        ushort4* dst = (ushort4*)xb;
        for (int i = bid * 256 + threadIdx.x; i < 1572864; i += 2048 * 256) {
            float4 v = src[i];
            ushort4 o;
            o.x = f2bf(v.x); o.y = f2bf(v.y); o.z = f2bf(v.z); o.w = f2bf(v.w);
            dst[i] = o;
        }
        return;
    }
    const float* src; ushort* dst; int K, N, bx, by;
    if (bid < 3776) {
        const int L = bid - 2048;
        src = wq; dst = wqbt; K = 768; N = 2304; bx = L % 72; by = L / 72;
    } else {
        const int L = bid - 3776;
        src = wo; dst = wobt; K = 768; N = 768; bx = L % 24; by = L / 24;
    }
    const int n0 = bx * 32, k0 = by * 32;
    const int c = threadIdx.x & 31, rb = threadIdx.x >> 5;
    #pragma unroll
    for (int i = 0; i < 4; ++i)
        tile[i * 8 + rb][c] = src[(size_t)(k0 + i * 8 + rb) * N + n0 + c];
    __syncthreads();
    #pragma unroll
    for (int i = 0; i < 4; ++i) {
        int nr = i * 8 + rb;
        dst[(size_t)(n0 + nr) * K + k0 + c] = f2bf(tile[c][nr]);
    }
}

// ---------------- GEMM1: 128x128xBK64, 4 waves, 2-buf, counted vmcnt (R6 proven) ----------------
// grid 1152 (xcd-swizzled), block 256. Scatter Q(scaled),K [B,H,S,D], V^T [B,H,D,S].
__global__ __launch_bounds__(256) void gemm_qkv_mfma(
    const ushort* __restrict__ A, const ushort* __restrict__ Bt,
    ushort* __restrict__ Qo, ushort* __restrict__ Ko, ushort* __restrict__ Vo)
{
    __shared__ ushort Al[2][8192];   // 2 x 128x64 bf16 = 32 KiB
    __shared__ ushort Bl[2][8192];   // 32 KiB
    const int tid = threadIdx.x, lane = tid & 63;
    const int wv = tid >> 6, lo = lane & 15, hi = lane >> 4;
    const int wr = wv >> 1, wc = wv & 1;
    const int L = blockIdx.x;
    const int nid = (L & 7) * 144 + (L >> 3);   // bijective: 1152 % 8 == 0
    const int n0 = (nid % 18) * 128, m0 = (nid / 18) * 128;

    auto stage = [&](int bi, int k0) {
        #pragma unroll
        for (int it = 0; it < 4; ++it) {
            const int p = it * 256 + tid;             // 1024 chunks of 16B
            const int row = p >> 3, ch = (p & 7) ^ (row & 7);
            GLDS16(A + (size_t)(m0 + row) * 768 + k0 + ch * 8,
                   &Al[bi][(it * 256 + (tid & 192)) * 8]);
        }
        #pragma unroll
        for (int it = 0; it < 4; ++it) {
            const int p = it * 256 + tid;
            const int row = p >> 3, ch = (p & 7) ^ (row & 7);
            GLDS16(Bt + (size_t)(n0 + row) * 768 + k0 + ch * 8,
                   &Bl[bi][(it * 256 + (tid & 192)) * 8]);
        }
    };

    f32x4 acc[4][4];
    #pragma unroll
    for (int i = 0; i < 4; ++i)
        #pragma unroll
        for (int j = 0; j < 4; ++j)
            acc[i][j] = (f32x4){0.f, 0.f, 0.f, 0.f};

    const int region = n0 / 768;                 // 0:Q 1:K 2:V
    const int h = ((n0 % 768) >> 6) + wc;

    stage(0, 0);
    stage(1, 64);

    int cur = 0;
    for (int t = 0; t < 12; ++t) {
        // tile t's loads (oldest 8) complete; tile t+1's stay in flight across barrier
        if (t < 11) asm volatile("s_waitcnt vmcnt(8)" ::: "memory");
        else        asm volatile("s_waitcnt vmcnt(0)" ::: "memory");
        __builtin_amdgcn_s_barrier();
        asm volatile("" ::: "memory");

        #pragma unroll
        for (int ks = 0; ks < 2; ++ks) {
            bf16x8 af[4], bfr[4];
            #pragma unroll
            for (int i = 0; i < 4; ++i) {
                const int ra = wr * 64 + i * 16 + lo;
                af[i] = *(const bf16x8*)&Al[cur][ra * 64 + (((ks * 4 + hi) ^ (ra & 7)) * 8)];
                const int rb = wc * 64 + i * 16 + lo;
                bfr[i] = *(const bf16x8*)&Bl[cur][rb * 64 + (((ks * 4 + hi) ^ (rb & 7)) * 8)];
            }
            if (region == 2) {
                #pragma unroll
                for (int mi = 0; mi < 4; ++mi)
                    #pragma unroll
                    for (int nj = 0; nj < 4; ++nj)
                        acc[mi][nj] = MFMA_BF16(af[mi], bfr[nj], acc[mi][nj]);
            } else {
                #pragma unroll
                for (int mi = 0; mi < 4; ++mi)
                    #pragma unroll
                    for (int nj = 0; nj < 4; ++nj)
                        acc[mi][nj] = MFMA_BF16(bfr[nj], af[mi], acc[mi][nj]);
            }
        }

        asm volatile("s_waitcnt lgkmcnt(0)" ::: "memory");
        __builtin_amdgcn_s_barrier();            // all waves done reading buf[cur]
        asm volatile("" ::: "memory");
        if (t + 2 < 12) stage(cur, (t + 2) * 64);  // overwrite freed buffer
        cur ^= 1;
    }

    if (region == 2) {
        #pragma unroll
        for (int mi = 0; mi < 4; ++mi) {
            const int m4 = m0 + wr * 64 + mi * 16 + hi * 4;
            const int b = m4 >> 10, s = m4 & 1023;
            #pragma unroll
            for (int nj = 0; nj < 4; ++nj) {
                const int d = nj * 16 + lo;
                ushort4 pk;
                pk.x = f2bf(acc[mi][nj][0]); pk.y = f2bf(acc[mi][nj][1]);
                pk.z = f2bf(acc[mi][nj][2]); pk.w = f2bf(acc[mi][nj][3]);
                *(ushort4*)&Vo[((size_t)(b * 12 + h) * 64 + d) * 1024 + s] = pk;
            }
        }
    } else {
        ushort* dst = region ? Ko : Qo;
        const float sc = region ? 1.0f : 0.18033688011112042f;  // (1/8)*log2(e) for Q
        #pragma unroll
        for (int mi = 0; mi < 4; ++mi) {
            const int s_idx = m0 + wr * 64 + mi * 16 + lo;
            const int b = s_idx >> 10, s = s_idx & 1023;
            const size_t base = ((size_t)(b * 12 + h) * 1024 + s) * 64;
            #pragma unroll
            for (int nj = 0; nj < 4; ++nj) {
                ushort4 pk;
                pk.x = f2bf(acc[mi][nj][0] * sc); pk.y = f2bf(acc[mi][nj][1] * sc);
                pk.z = f2bf(acc[mi][nj][2] * sc); pk.w = f2bf(acc[mi][nj][3] * sc);
                *(ushort4*)&dst[base + nj * 16 + hi * 4] = pk;
            }
        }
    }
}

// ---------------- Flash attention, bf16 MFMA, no-max softmax, S^T trick, setprio ----------------
__global__ __launch_bounds__(256) void attn_mfma_kernel(
    const ushort* __restrict__ Qg, const ushort* __restrict__ Kg,
    const ushort* __restrict__ Vg, ushort* __restrict__ AO)
{
    __shared__ ushort Kl[2][4096];
    __shared__ ushort Vl[2][4096];
    __shared__ ushort Pl[4][32 * 72];

    const int tid = threadIdx.x, lane = tid & 63;
    const int wv = tid >> 6, lo = lane & 15, hi = lane >> 4;
    const int L = blockIdx.x;
    const int xcd = L & 7, g = L >> 3;
    const int qb = g / 12;
    const int bh = xcd * 12 + (g % 12);
    const int b = bh / 12, h = bh % 12;
    const size_t kvbase = (size_t)bh * (1024 * 64);

    bf16x8 qa[2][2];
    const int qrow0 = qb * 128 + wv * 32;
    #pragma unroll
    for (int mi = 0; mi < 2; ++mi)
        #pragma unroll
        for (int ks = 0; ks < 2; ++ks)
            qa[mi][ks] = *(const bf16x8*)&Qg[kvbase + (size_t)(qrow0 + mi * 16 + lo) * 64 + ks * 32 + hi * 8];

    f32x4 o[2][4];
    float lp[2] = {0.f, 0.f};
    #pragma unroll
    for (int mi = 0; mi < 2; ++mi)
        #pragma unroll
        for (int dj = 0; dj < 4; ++dj) o[mi][dj] = (f32x4){0.f, 0.f, 0.f, 0.f};

    auto stage = [&](int bi, int kt) {
        #pragma unroll
        for (int it = 0; it < 2; ++it) {
            const int p = it * 256 + tid;
            const int row = p >> 3, ch = (p & 7) ^ (row & 7);
            GLDS16(Kg + kvbase + (size_t)(kt + row) * 64 + ch * 8, &Kl[bi][(it * 256 + (tid & 192)) * 8]);
        }
        #pragma unroll
        for (int it = 0; it < 2; ++it) {
            const int p = it * 256 + tid;
            const int row = p >> 3, ch = (p & 7) ^ (row & 7);
            GLDS16(Vg + kvbase + (size_t)row * 1024 + kt + ch * 8, &Vl[bi][(it * 256 + (tid & 192)) * 8]);
        }
    };

    stage(0, 0);
    __syncthreads();

    for (int t = 0; t < 16; ++t) {
        const int cur = t & 1;
        if (t < 15) stage(cur ^ 1, (t + 1) * 64);

        f32x4 s[2][4];
        #pragma unroll
        for (int mi = 0; mi < 2; ++mi)
            #pragma unroll
            for (int nj = 0; nj < 4; ++nj) s[mi][nj] = (f32x4){0.f, 0.f, 0.f, 0.f};
        #pragma unroll
        for (int ks = 0; ks < 2; ++ks) {
            bf16x8 kb[4];
            #pragma unroll
            for (int nj = 0; nj < 4; ++nj) {
                const int key = nj * 16 + lo, c = ks * 4 + hi;
                kb[nj] = *(const bf16x8*)&Kl[cur][key * 64 + ((c ^ (key & 7)) * 8)];
            }
            __builtin_amdgcn_s_setprio(1);
            #pragma unroll
            for (int mi = 0; mi < 2; ++mi)
                #pragma unroll
                for (int nj = 0; nj < 4; ++nj)
                    s[mi][nj] = MFMA_BF16(kb[nj], qa[mi][ks], s[mi][nj]);
            __builtin_amdgcn_s_setprio(0);
        }

        #pragma unroll
        for (int mi = 0; mi < 2; ++mi) {
            #pragma unroll
            for (int nj = 0; nj < 4; ++nj) {
                const unsigned int u0 = __float_as_uint(fexp2(s[mi][nj][0]));
                const unsigned int u1 = __float_as_uint(fexp2(s[mi][nj][1]));
                const unsigned int u2 = __float_as_uint(fexp2(s[mi][nj][2]));
                const unsigned int u3 = __float_as_uint(fexp2(s[mi][nj][3]));
                const float t0 = __uint_as_float(u0 & 0xFFFF0000u);
                const float t1 = __uint_as_float(u1 & 0xFFFF0000u);
                const float t2 = __uint_as_float(u2 & 0xFFFF0000u);
                const float t3 = __uint_as_float(u3 & 0xFFFF0000u);
                lp[mi] += (t0 + t1) + (t2 + t3);
                ushort4 pk;
                pk.x = (ushort)(u0 >> 16); pk.y = (ushort)(u1 >> 16);
                pk.z = (ushort)(u2 >> 16); pk.w = (ushort)(u3 >> 16);
                *(ushort4*)&Pl[wv][(mi * 16 + lo) * 72 + nj * 16 + hi * 4] = pk;
            }
        }

        #pragma unroll
        for (int ks = 0; ks < 2; ++ks) {
            bf16x8 pa[2];
            #pragma unroll
            for (int mi = 0; mi < 2; ++mi)
                pa[mi] = *(const bf16x8*)&Pl[wv][(mi * 16 + lo) * 72 + ks * 32 + hi * 8];
            bf16x8 vb[4];
            #pragma unroll
            for (int dj = 0; dj < 4; ++dj) {
                const int d = dj * 16 + lo, c = ks * 4 + hi;
                vb[dj] = *(const bf16x8*)&Vl[cur][d * 64 + ((c ^ (d & 7)) * 8)];
            }
            __builtin_amdgcn_s_setprio(1);
            #pragma unroll
            for (int mi = 0; mi < 2; ++mi)
                #pragma unroll
                for (int dj = 0; dj < 4; ++dj)
                    o[mi][dj] = MFMA_BF16(pa[mi], vb[dj], o[mi][dj]);
            __builtin_amdgcn_s_setprio(0);
        }
        __syncthreads();
    }

    #pragma unroll
    for (int mi = 0; mi < 2; ++mi) {
        float l = lp[mi];
        l += __shfl_xor(l, 16);
        l += __shfl_xor(l, 32);
        #pragma unroll
        for (int r = 0; r < 4; ++r) {
            const float lr = __shfl(l, hi * 4 + r, 16);
            const float rcp = 1.0f / lr;
            const int srow = qrow0 + mi * 16 + hi * 4 + r;
            #pragma unroll
            for (int dj = 0; dj < 4; ++dj)
                AO[((size_t)(b * 1024 + srow)) * 768 + h * 64 + dj * 16 + lo] =
                    f2bf(o[mi][dj][r] * rcp);
        }
    }
}

// ---------------- GEMM2: 128x128xBK64, 2-buf counted vmcnt; fp32 out + bias (R6 proven) ----------------
__global__ __launch_bounds__(256) void gemm_out_mfma(
    const ushort* __restrict__ A, const ushort* __restrict__ Bt,
    const float* __restrict__ bias, float* __restrict__ C)
{
    __shared__ ushort Al[2][8192];
    __shared__ ushort Bl[2][8192];
    const int tid = threadIdx.x, lane = tid & 63;
    const int wv = tid >> 6, lo = lane & 15, hi = lane >> 4;
    const int wr = wv >> 1, wc = wv & 1;
    const int L = blockIdx.x;
    const int nid = (L & 7) * 48 + (L >> 3);    // bijective: 384 % 8 == 0
    const int n0 = (nid % 6) * 128, m0 = (nid / 6) * 128;

    auto stage = [&](int bi, int k0) {
        #pragma unroll
        for (int it = 0; it < 4; ++it) {
            const int p = it * 256 + tid;
            const int row = p >> 3, ch = (p & 7) ^ (row & 7);
            GLDS16(A + (size_t)(m0 + row) * 768 + k0 + ch * 8,
                   &Al[bi][(it * 256 + (tid & 192)) * 8]);
        }
        #pragma unroll
        for (int it = 0; it < 4; ++it) {
            const int p = it * 256 + tid;
            const int row = p >> 3, ch = (p & 7) ^ (row & 7);
            GLDS16(Bt + (size_t)(n0 + row) * 768 + k0 + ch * 8,
                   &Bl[bi][(it * 256 + (tid & 192)) * 8]);
        }
    };

    f32x4 acc[4][4];
    #pragma unroll
    for (int i = 0; i < 4; ++i)
        #pragma unroll
        for (int j = 0; j < 4; ++j)
            acc[i][j] = (f32x4){0.f, 0.f, 0.f, 0.f};

    stage(0, 0);
    stage(1, 64);

    int cur = 0;
    for (int t = 0; t < 12; ++t) {
        if (t < 11) asm volatile("s_waitcnt vmcnt(8)" ::: "memory");
        else        asm volatile("s_waitcnt vmcnt(0)" ::: "memory");
        __builtin_amdgcn_s_barrier();
        asm volatile("" ::: "memory");

        #pragma unroll
        for (int ks = 0; ks < 2; ++ks) {
            bf16x8 af[4], bfr[4];
            #pragma unroll
            for (int i = 0; i < 4; ++i) {
                const int ra = wr * 64 + i * 16 + lo;
                af[i] = *(const bf16x8*)&Al[cur][ra * 64 + (((ks * 4 + hi) ^ (ra & 7)) * 8)];
                const int rb = wc * 64 + i * 16 + lo;
                bfr[i] = *(const bf16x8*)&Bl[cur][rb * 64 + (((ks * 4 + hi) ^ (rb & 7)) * 8)];
            }
            #pragma unroll
            for (int mi = 0; mi < 4; ++mi)
                #pragma unroll
                for (int nj = 0; nj < 4; ++nj)
                    acc[mi][nj] = MFMA_BF16(bfr[nj], af[mi], acc[mi][nj]);
        }

        asm volatile("s_waitcnt lgkmcnt(0)" ::: "memory");
        __builtin_amdgcn_s_barrier();
        asm volatile("" ::: "memory");
        if (t + 2 < 12) stage(cur, (t + 2) * 64);
        cur ^= 1;
    }

    const int ncol0 = n0 + wc * 64;
    #pragma unroll
    for (int mi = 0; mi < 4; ++mi) {
        const int m = m0 + wr * 64 + mi * 16 + lo;
        #pragma unroll
        for (int nj = 0; nj < 4; ++nj) {
            const int nb = ncol0 + nj * 16 + hi * 4;
            const float4 bv = *reinterpret_cast<const float4*>(&bias[nb]);
            float4 ov;
            ov.x = acc[mi][nj][0] + bv.x; ov.y = acc[mi][nj][1] + bv.y;
            ov.z = acc[mi][nj][2] + bv.z; ov.w = acc[mi][nj][3] + bv.w;
            *reinterpret_cast<float4*>(&C[(size_t)m * 768 + nb]) = ov;
        }
    }
}

extern "C" void kernel_launch(void* const* d_in, const int* in_sizes, int n_in,
                              void* d_out, int out_size, void* d_ws, size_t ws_size,
                              hipStream_t stream) {
    const float* x     = (const float*)d_in[0];
    const float* w_qkv = (const float*)d_in[1];
    const float* w_out = (const float*)d_in[2];
    const float* b_out = (const float*)d_in[3];
    float* out = (float*)d_out;

    (void)in_sizes; (void)n_in; (void)out_size; (void)ws_size;

    ushort* xb   = (ushort*)d_ws;            // 6291456  (x bf16)
    ushort* wqbt = xb + 6291456;             // 1769472  (w_qkv^T bf16 [2304][768])
    ushort* wobt = wqbt + 1769472;           // 589824   (w_out^T bf16 [768][768])
    ushort* Qs   = wobt + 589824;            // 6291456  (Q*0.125*log2e, [B,H,S,D])
    ushort* Ks   = Qs + 6291456;             // 6291456  ([B,H,S,D])
    ushort* Vt   = Ks + 6291456;             // 6291456  ([B,H,D,S])
    ushort* AO   = Vt + 6291456;             // 6291456  ([B,S,E] bf16)

    prep_kernel<<<4352, 256, 0, stream>>>(x, w_qkv, w_out, xb, wqbt, wobt);
    gemm_qkv_mfma<<<1152, 256, 0, stream>>>(xb, wqbt, Qs, Ks, Vt);
    attn_mfma_kernel<<<768, 256, 0, stream>>>(Qs, Ks, Vt, AO);
    gemm_out_mfma<<<384, 256, 0, stream>>>(AO, wobt, b_out, out);
}